// Round 1
// baseline (295.018 us; speedup 1.0000x reference)
//
#include <hip/hip_runtime.h>

// NCC weight loss, fused single-kernel implementation.
// Dims fixed by the problem: (N=2, C=1, D=160, H=192, W=224), win=5, fp32.
#define N_  2
#define D_  160
#define H_  192
#define W_  224
#define TW  32            // tile width  (x)
#define TH  8             // tile height (y)
#define ZCH 32            // z-chunk length per block
#define NZC (D_/ZCH)      // 5 chunks
#define HWH (TW+4)        // 36 halo width
#define HHH (TH+4)        // 12 halo height
#define TOT (N_*D_*H_*W_) // 13,762,560

__global__ __launch_bounds__(256) void ncc_kernel(
    const float* __restrict__ I, const float* __restrict__ J,
    const float* __restrict__ Wm, float* __restrict__ out)
{
    __shared__ float q [5][HHH][HWH];  // quantity planes (I,J,I2,J2,IJ)
    __shared__ float sx[5][HHH][TW];   // after x box-sum
    __shared__ float red[4];

    const int tx  = threadIdx.x, ty = threadIdx.y;
    const int tid = ty * TW + tx;
    const int bx  = blockIdx.x, by = blockIdx.y;
    const int n   = blockIdx.z / NZC;
    const int zc  = blockIdx.z % NZC;
    const int c0  = zc * ZCH;

    const int wbase = bx * TW - 2;
    const int hbase = by * TH - 2;
    const int w_out = bx * TW + tx;
    const int h_out = by * TH + ty;

    // z-direction ring buffer (5 planes) per quantity, running sums
    float ring[5][5];
    float zs[5];
#pragma unroll
    for (int a = 0; a < 5; ++a) {
        zs[a] = 0.f;
#pragma unroll
        for (int s = 0; s < 5; ++s) ring[a][s] = 0.f;
    }

    float acc = 0.f;
    const int nsteps = ZCH + 4;   // 2 warm-up planes below, 2 tail planes above

    for (int s = 0; s < nsteps; ++s) {
        const int z = c0 - 2 + s;
        const bool zin = (unsigned)z < (unsigned)D_;

        // Phase A: load halo plane of I,J; write 5 quantity planes to LDS
        for (int p = tid; p < HHH * HWH; p += 256) {
            const int ly = p / HWH;
            const int lx = p - ly * HWH;
            const int w  = wbase + lx;
            const int h  = hbase + ly;
            float iv = 0.f, jv = 0.f;
            if (zin && (unsigned)w < (unsigned)W_ && (unsigned)h < (unsigned)H_) {
                const int g = ((n * D_ + z) * H_ + h) * W_ + w;
                iv = I[g];
                jv = J[g];
            }
            q[0][ly][lx] = iv;
            q[1][ly][lx] = jv;
            q[2][ly][lx] = iv * iv;
            q[3][ly][lx] = jv * jv;
            q[4][ly][lx] = iv * jv;
        }
        __syncthreads();

        // Phase B: x box-sums (36 -> 32 per row), 12*32 = 384 positions
        for (int p = tid; p < HHH * TW; p += 256) {
            const int ly = p >> 5;
            const int x  = p & (TW - 1);
            float a0 = 0.f, a1 = 0.f, a2 = 0.f, a3 = 0.f, a4 = 0.f;
#pragma unroll
            for (int k = 0; k < 5; ++k) {
                a0 += q[0][ly][x + k];
                a1 += q[1][ly][x + k];
                a2 += q[2][ly][x + k];
                a3 += q[3][ly][x + k];
                a4 += q[4][ly][x + k];
            }
            sx[0][ly][x] = a0;
            sx[1][ly][x] = a1;
            sx[2][ly][x] = a2;
            sx[3][ly][x] = a3;
            sx[4][ly][x] = a4;
        }
        __syncthreads();

        // Phase C: y box-sums -> per-thread plane value; z-ring update; output
        float P[5];
#pragma unroll
        for (int a = 0; a < 5; ++a) {
            float v = 0.f;
#pragma unroll
            for (int k = 0; k < 5; ++k) v += sx[a][ty + k][tx];
            P[a] = v;
        }
        const int slot = s % 5;
#pragma unroll
        for (int a = 0; a < 5; ++a) {
            zs[a]  -= ring[a][slot];
            ring[a][slot] = P[a];
            zs[a]  += P[a];
        }

        const int zo = z - 2;
        if (zo >= c0) {  // zo < c0+ZCH guaranteed by loop bound; zo < D guaranteed
            const float inv125 = 1.0f / 125.0f;
            const float cross = zs[4] - zs[0] * zs[1] * inv125;
            const float ivar  = zs[2] - zs[0] * zs[0] * inv125;
            const float jvar  = zs[3] - zs[1] * zs[1] * inv125;
            const float cc    = (cross * cross) / (ivar * jvar + 1e-8f);
            const int g = ((n * D_ + zo) * H_ + h_out) * W_ + w_out;
            acc += cc * Wm[g];
        }
        // next Phase A writes q (not read in C); sync after A protects sx
    }

    // Block reduction: wave64 shuffle, then cross-wave via LDS
#pragma unroll
    for (int off = 32; off > 0; off >>= 1)
        acc += __shfl_down(acc, off, 64);
    const int wave = tid >> 6;
    const int lane = tid & 63;
    if (lane == 0) red[wave] = acc;
    __syncthreads();
    if (tid == 0) {
        const float t = red[0] + red[1] + red[2] + red[3];
        atomicAdd(out, t * (-1.0f / (float)TOT));
    }
}

extern "C" void kernel_launch(void* const* d_in, const int* in_sizes, int n_in,
                              void* d_out, int out_size, void* d_ws, size_t ws_size,
                              hipStream_t stream)
{
    const float* I  = (const float*)d_in[0];
    const float* J  = (const float*)d_in[1];
    const float* Wm = (const float*)d_in[2];
    float* out = (float*)d_out;

    // d_out is poisoned before every launch; the kernel atomically accumulates.
    hipMemsetAsync(out, 0, sizeof(float), stream);

    dim3 grid(W_ / TW, H_ / TH, N_ * NZC);  // (7, 24, 10) = 1680 blocks
    dim3 block(TW, TH);                     // (32, 8) = 256 threads
    hipLaunchKernelGGL(ncc_kernel, grid, block, 0, stream, I, J, Wm, out);
}

// Round 2
// 251.102 us; speedup vs baseline: 1.1749x; 1.1749x over previous
//
#include <hip/hip_runtime.h>

// NCC weight loss, fused single-kernel, z-streaming with register z-ring
// upstream of the LDS 2D box filter; all LDS traffic vectorized b64/b128.
// Dims fixed: (N=2, C=1, D=160, H=192, W=224), win=5, fp32.
#define N_  2
#define D_  160
#define H_  192
#define W_  224
#define TW  32            // output tile width (x)
#define TH  8             // output tile height (y)
#define ZCH 32            // z-chunk per block
#define NZC (D_/ZCH)      // 5
#define HWH (TW+4)        // 36 halo width
#define HHH (TH+4)        // 12 halo height
#define TOT (N_*D_*H_*W_) // 13,762,560

__global__ __launch_bounds__(256) void ncc_kernel(
    const float* __restrict__ I, const float* __restrict__ J,
    const float* __restrict__ Wm, float* __restrict__ out)
{
    // z-summed quantity planes (I,J,I2,J2,IJ) and x-box-summed planes
    __shared__ __align__(16) float zsL[5][HHH][HWH]; // rows 144B (16B-aligned)
    __shared__ __align__(16) float sx [5][HHH][TW];  // rows 128B
    __shared__ float red[4];

    const int tid = threadIdx.x;
    const int bx = blockIdx.x, by = blockIdx.y;
    const int n  = blockIdx.z / NZC;
    const int c0 = (blockIdx.z % NZC) * ZCH;
    const int wbase = bx * TW - 2;
    const int hbase = by * TH - 2;

    // ---- Phase A ownership: 216 threads own 2 adjacent halo columns each ----
    const bool aAct = tid < 216;
    const int arow = tid / 18;          // 0..11
    const int ag   = tid % 18;          // 0..17 (column pair)
    const int ah   = hbase + arow;
    const int aw0  = wbase + 2 * ag;    // even -> float2-aligned in global
    const bool hok  = (unsigned)ah < (unsigned)H_;
    const bool w0ok = (unsigned)aw0 < (unsigned)W_;
    const bool w1ok = (unsigned)(aw0 + 1) < (unsigned)W_;
    const bool v2   = w0ok && w1ok;

    // per-column z-ring of raw I,J (5 deep) + incremental z-sums of 5 quantities
    float rI0[5], rJ0[5], rI1[5], rJ1[5];
    float zs0[5], zs1[5];
#pragma unroll
    for (int k = 0; k < 5; ++k) { rI0[k]=0.f; rJ0[k]=0.f; rI1[k]=0.f; rJ1[k]=0.f; }
#pragma unroll
    for (int a = 0; a < 5; ++a) { zs0[a]=0.f; zs1[a]=0.f; }

    // ---- Phase B ownership: 96 threads, 4 x-outputs each ----
    const bool bAct = tid < 96;
    const int brow = tid >> 3;          // 0..11
    const int bx0  = (tid & 7) * 4;     // 0,4,...,28

    // ---- Phase C ownership: 64 threads, 4 outputs each ----
    const bool cAct = tid < 64;
    const int cty = tid >> 3;           // 0..7
    const int cx0 = (tid & 7) * 4;      // 0..28
    const int ch  = by * TH + cty;
    const int cw  = bx * TW + cx0;      // multiple of 4 -> float4-aligned

    float acc = 0.f;
    const float inv125 = 1.0f / 125.0f;

    for (int s = 0; s < ZCH + 4; ++s) {
        const int z = c0 - 2 + s;
        const bool zin = (unsigned)z < (unsigned)D_;

        // ---------- Phase A: load plane z, update register z-sums, stage to LDS
        if (aAct) {
            float iv0=0.f, iv1=0.f, jv0=0.f, jv1=0.f;
            if (zin && hok) {
                const int base = ((n * D_ + z) * H_ + ah) * W_;
                if (v2) {
                    const float2 i2 = *(const float2*)&I[base + aw0];
                    const float2 j2 = *(const float2*)&J[base + aw0];
                    iv0 = i2.x; iv1 = i2.y; jv0 = j2.x; jv1 = j2.y;
                } else {
                    if (w0ok) { iv0 = I[base + aw0];     jv0 = J[base + aw0]; }
                    if (w1ok) { iv1 = I[base + aw0 + 1]; jv1 = J[base + aw0 + 1]; }
                }
            }
            {   // column 0: subtract oldest, add newest, shift ring
                const float oi = rI0[0], oj = rJ0[0];
                zs0[0] += iv0 - oi;
                zs0[1] += jv0 - oj;
                zs0[2] += iv0*iv0 - oi*oi;
                zs0[3] += jv0*jv0 - oj*oj;
                zs0[4] += iv0*jv0 - oi*oj;
#pragma unroll
                for (int k = 0; k < 4; ++k) { rI0[k]=rI0[k+1]; rJ0[k]=rJ0[k+1]; }
                rI0[4] = iv0; rJ0[4] = jv0;
            }
            {   // column 1
                const float oi = rI1[0], oj = rJ1[0];
                zs1[0] += iv1 - oi;
                zs1[1] += jv1 - oj;
                zs1[2] += iv1*iv1 - oi*oi;
                zs1[3] += jv1*jv1 - oj*oj;
                zs1[4] += iv1*jv1 - oi*oj;
#pragma unroll
                for (int k = 0; k < 4; ++k) { rI1[k]=rI1[k+1]; rJ1[k]=rJ1[k+1]; }
                rI1[4] = iv1; rJ1[4] = jv1;
            }
#pragma unroll
            for (int a = 0; a < 5; ++a) {
                *(float2*)&zsL[a][arow][2*ag] = make_float2(zs0[a], zs1[a]);
            }
        }
        __syncthreads();

        // ---------- Phase B: x box-sum (36 -> 32), 4 outputs per thread
        if (bAct) {
#pragma unroll
            for (int a = 0; a < 5; ++a) {
                const float4 v0 = *(const float4*)&zsL[a][brow][bx0];
                const float4 v1 = *(const float4*)&zsL[a][brow][bx0 + 4];
                const float m  = v0.y + v0.z + v0.w;       // middle prefix
                const float u1 = v1.x + v1.y;
                const float u2 = u1 + v1.z;
                const float o0 = v0.x + m + v1.x;
                const float o1 = m + u1;
                const float o2 = (v0.z + v0.w) + u2;
                const float o3 = v0.w + (u2 + v1.w);
                *(float4*)&sx[a][brow][bx0] = make_float4(o0, o1, o2, o3);
            }
        }
        __syncthreads();

        // ---------- Phase C: y box-sum + cc + weighted accumulate, 4 outputs/thread
        const int zo = z - 2;
        if (cAct && zo >= c0) {
            float4 S[5];
#pragma unroll
            for (int a = 0; a < 5; ++a) {
                float4 v = *(const float4*)&sx[a][cty][cx0];
#pragma unroll
                for (int k = 1; k < 5; ++k) {
                    const float4 w = *(const float4*)&sx[a][cty + k][cx0];
                    v.x += w.x; v.y += w.y; v.z += w.z; v.w += w.w;
                }
                S[a] = v;
            }
            const float4 wm = *(const float4*)&Wm[((n * D_ + zo) * H_ + ch) * W_ + cw];
            {
                const float cr = S[4].x - S[0].x * S[1].x * inv125;
                const float vi = S[2].x - S[0].x * S[0].x * inv125;
                const float vj = S[3].x - S[1].x * S[1].x * inv125;
                acc += wm.x * (cr * cr) * __builtin_amdgcn_rcpf(vi * vj + 1e-8f);
            }
            {
                const float cr = S[4].y - S[0].y * S[1].y * inv125;
                const float vi = S[2].y - S[0].y * S[0].y * inv125;
                const float vj = S[3].y - S[1].y * S[1].y * inv125;
                acc += wm.y * (cr * cr) * __builtin_amdgcn_rcpf(vi * vj + 1e-8f);
            }
            {
                const float cr = S[4].z - S[0].z * S[1].z * inv125;
                const float vi = S[2].z - S[0].z * S[0].z * inv125;
                const float vj = S[3].z - S[1].z * S[1].z * inv125;
                acc += wm.z * (cr * cr) * __builtin_amdgcn_rcpf(vi * vj + 1e-8f);
            }
            {
                const float cr = S[4].w - S[0].w * S[1].w * inv125;
                const float vi = S[2].w - S[0].w * S[0].w * inv125;
                const float vj = S[3].w - S[1].w * S[1].w * inv125;
                acc += wm.w * (cr * cr) * __builtin_amdgcn_rcpf(vi * vj + 1e-8f);
            }
        }
        // next Phase A writes zsL: safe — all waves passed the post-B barrier,
        // and Phase C only reads sx.
    }

    // Block reduction: wave64 shuffle, then cross-wave via LDS
#pragma unroll
    for (int off = 32; off > 0; off >>= 1)
        acc += __shfl_down(acc, off, 64);
    const int wave = tid >> 6;
    const int lane = tid & 63;
    if (lane == 0) red[wave] = acc;
    __syncthreads();
    if (tid == 0) {
        const float t = red[0] + red[1] + red[2] + red[3];
        atomicAdd(out, t * (-1.0f / (float)TOT));
    }
}

extern "C" void kernel_launch(void* const* d_in, const int* in_sizes, int n_in,
                              void* d_out, int out_size, void* d_ws, size_t ws_size,
                              hipStream_t stream)
{
    const float* I  = (const float*)d_in[0];
    const float* J  = (const float*)d_in[1];
    const float* Wm = (const float*)d_in[2];
    float* out = (float*)d_out;

    hipMemsetAsync(out, 0, sizeof(float), stream);

    dim3 grid(W_ / TW, H_ / TH, N_ * NZC);  // (7, 24, 10) = 1680 blocks
    dim3 block(256);
    hipLaunchKernelGGL(ncc_kernel, grid, block, 0, stream, I, J, Wm, out);
}